// Round 8
// baseline (157.682 us; speedup 1.0000x reference)
//
#include <hip/hip_runtime.h>

typedef unsigned int u32;
typedef unsigned long long u64;
typedef unsigned char u8;

// Marching-tets tables (from reference)
__constant__ int c_tt[16][6] = {
  {-1,-1,-1,-1,-1,-1},{1,0,2,-1,-1,-1},{4,0,3,-1,-1,-1},{1,4,2,1,3,4},
  {3,1,5,-1,-1,-1},{2,3,0,2,5,3},{1,4,0,1,5,4},{4,2,5,-1,-1,-1},
  {4,5,2,-1,-1,-1},{4,1,0,4,5,1},{3,2,0,3,5,2},{1,3,5,-1,-1,-1},
  {4,1,2,4,3,1},{3,0,4,-1,-1,-1},{2,0,1,-1,-1,-1},{-1,-1,-1,-1,-1,-1}};
__constant__ int c_ntri[16] = {0,1,1,2,1,2,2,1,1,2,2,1,2,1,1,0};
__constant__ int c_kuhn[6][4] = {{0,1,3,7},{0,2,3,7},{0,1,5,7},{0,2,6,7},{0,4,5,7},{0,4,6,7}};
__constant__ int c_e0[6] = {0,0,0,1,1,2};
__constant__ int c_e1[6] = {1,2,3,2,3,3};

// ---------------- scan helpers (wave64) ----------------
__device__ __forceinline__ u32 wave_incscan_u32(u32 v) {
  int lane = threadIdx.x & 63;
#pragma unroll
  for (int d = 1; d < 64; d <<= 1) {
    u32 n = __shfl_up(v, (unsigned)d, 64);
    if (lane >= d) v += n;
  }
  return v;
}
__device__ __forceinline__ u64 wave_incscan_u64(u64 v) {
  int lane = threadIdx.x & 63;
#pragma unroll
  for (int d = 1; d < 64; d <<= 1) {
    u32 lo = __shfl_up((u32)v, (unsigned)d, 64);
    u32 hi = __shfl_up((u32)(v >> 32), (unsigned)d, 64);
    u64 n = ((u64)hi << 32) | (u64)lo;
    if (lane >= d) v += n;
  }
  return v;
}
__device__ __forceinline__ u32 block_exscan_u32(u32 v, u32* wsums, u32* total) {
  int tid = threadIdx.x, lane = tid & 63, w = tid >> 6, nw = blockDim.x >> 6;
  u32 inc = wave_incscan_u32(v);
  if (lane == 63) wsums[w] = inc;
  __syncthreads();
  u32 woff = 0, tot = 0;
  for (int i = 0; i < nw; i++) { u32 s = wsums[i]; tot += s; if (i < w) woff += s; }
  __syncthreads();
  if (total) *total = tot;
  return woff + inc - v;
}
__device__ __forceinline__ u64 block_exscan_u64(u64 v, u64* wsums, u64* total) {
  int tid = threadIdx.x, lane = tid & 63, w = tid >> 6, nw = blockDim.x >> 6;
  u64 inc = wave_incscan_u64(v);
  if (lane == 63) wsums[w] = inc;
  __syncthreads();
  u64 woff = 0, tot = 0;
  for (int i = 0; i < nw; i++) { u64 s = wsums[i]; tot += s; if (i < w) woff += s; }
  __syncthreads();
  if (total) *total = tot;
  return woff + inc - v;
}

// ---------------- Kernel A: lpack (vertex blocks) + tcode (tet blocks) + block sums ----------------
// NOTE (R6 lesson): no device fences / same-address tickets — per-XCD L2s are non-coherent; a
// per-block __threadfence()+atomic ticket cost ~470 µs. Separate 2-block kC is ~4 µs.
template <int CR>
__global__ __launch_bounds__(256) void kA(const float* __restrict__ sdf, u32* __restrict__ lpack,
                                          u8* __restrict__ tcode, u32* __restrict__ bsumV,
                                          u32* __restrict__ bsumT, int NV, int T, int nvb, int rr) {
  const int R = CR ? CR : rr;
  const int R1 = R + 1, R1sq = R1 * R1;
  __shared__ u32 ws[4];
  int tid = threadIdx.x, bid = blockIdx.x;
  if (bid < nvb) {
    int v = bid * 256 + tid;
    u32 m = 0;
    if (v < NV) {
      int z = v % R1, tq = v / R1, y = tq % R1, x = tq / R1;
      bool o = sdf[v] > 0.0f;
      bool bx = x < R, by = y < R, bz = z < R;
      if (bz && (sdf[v + 1] > 0.0f) != o) m |= 1;
      if (by && (sdf[v + R1] > 0.0f) != o) m |= 2;
      if (by && bz && (sdf[v + R1 + 1] > 0.0f) != o) m |= 4;
      if (bx && (sdf[v + R1sq] > 0.0f) != o) m |= 8;
      if (bx && bz && (sdf[v + R1sq + 1] > 0.0f) != o) m |= 16;
      if (bx && by && (sdf[v + R1sq + R1] > 0.0f) != o) m |= 32;
      if (bx && by && bz && (sdf[v + R1sq + R1 + 1] > 0.0f) != o) m |= 64;
    }
    u32 tot;
    u32 ex = block_exscan_u32(__popc(m), ws, &tot);
    if (v < NV) lpack[v] = (ex << 7) | m;
    if (tid == 0) bsumV[bid] = tot;
  } else {
    int t = (bid - nvb) * 256 + tid;
    u32 packed = 0;
    if (t < T) {
      int c = t / 6, k = t - 6 * c;
      int z = c % R, tq = c / R, y = tq % R, x = tq / R;
      int v000 = (x * R1 + y) * R1 + z;
      int coff[8] = {0, R1sq, R1, R1sq + R1, 1, R1sq + 1, R1 + 1, R1sq + R1 + 1};
      int code = 0;
#pragma unroll
      for (int j = 0; j < 4; j++)
        code |= (sdf[v000 + coff[c_kuhn[k][j]]] > 0.0f ? 1 : 0) << j;
      tcode[t] = (u8)code;
      int n = c_ntri[code];
      packed = (n == 1 ? 1u : 0u) | (n == 2 ? (1u << 16) : 0u);
    }
    u32 tot;
    block_exscan_u32(packed, ws, &tot);
    if (tid == 0) bsumT[bid - nvb] = tot;
  }
}

// ---------------- Kernel C: two independent aux scans ----------------
__global__ __launch_bounds__(1024) void kC(const u32* __restrict__ bsumV, u32* __restrict__ boffV,
                                           int nvb, const u32* __restrict__ bsumT,
                                           u64* __restrict__ boffT, int ntb, u32* __restrict__ hdr) {
  if (blockIdx.x == 0) {
    __shared__ u32 ws32[16];
    u32 carry = 0;
    for (int base = 0; base < nvb; base += 1024) {
      int i = base + threadIdx.x;
      u32 v = (i < nvb) ? bsumV[i] : 0;
      u32 tot;
      u32 ex = block_exscan_u32(v, ws32, &tot);
      if (i < nvb) boffV[i] = carry + ex;
      carry += tot;
    }
    if (threadIdx.x == 0) hdr[0] = carry;               // E
  } else {
    __shared__ u64 ws64[16];
    u64 carry = 0;
    for (int base = 0; base < ntb; base += 1024) {
      int i = base + threadIdx.x;
      u32 p = (i < ntb) ? bsumT[i] : 0;
      u64 v = (u64)(p & 0xffffu) | ((u64)(p >> 16) << 32);
      u64 tot;
      u64 ex = block_exscan_u64(v, ws64, &tot);
      if (i < ntb) boffT[i] = carry + ex;
      carry += tot;
    }
    if (threadIdx.x == 0) { hdr[1] = (u32)carry; hdr[2] = (u32)(carry >> 32); } // F1, F2
  }
}

// ---------------- Kernel D: PERSISTENT blocks grid-striding over uv | verts | faces virtual blocks ----
// 2048 physical blocks (8/CU) loop over 19.5k virtual block ids; every CU holds a mix of
// streaming (uv) and latency-bound (verts/faces) work at all times; no block turnover.
template <int CR, int CNU>
__global__ __launch_bounds__(256) void kD(const float* __restrict__ verts, const float* __restrict__ sdf,
                                          const float* __restrict__ deform, const u32* __restrict__ lpack,
                                          const u32* __restrict__ boffV, const u8* __restrict__ tcode,
                                          const u64* __restrict__ boffT, const u32* __restrict__ hdr,
                                          float* __restrict__ out, int NV, int T, int nvb, int nuvb,
                                          int ntb, int rr, int nuu, float sdefs, double inv) {
  const int R = CR ? CR : rr;
  const int R1 = R + 1, R1sq = R1 * R1;
  const u32 NU = CNU ? CNU : (u32)nuu;
  __shared__ u32 ws[4];
  int tid = threadIdx.x;
  // hoisted section constants (hdr written by kC, visible at dispatch)
  u32 E = hdr[0], F1 = hdr[1], F2 = hdr[2];
  u32 F = F1 + 2u * F2;
  size_t fb = (size_t)3 * E;                     // faces section start (float index)
  size_t A = fb + (size_t)3 * F;                 // uv section start
  size_t ub = A + (size_t)8 * NU * NU;           // uv_idx section start
  u32 sh = (u32)(A & 3);
  size_t A4 = A - sh;
  u32 totalf = 8u * NU * NU;                     // < 2^25 for NU < 2048
  float padf = (float)(0.9 * inv);
  int deltas[7] = {1, R1, R1 + 1, R1sq, R1sq + 1, R1sq + R1, R1sq + R1 + 1};
  int coff[8] = {0, R1sq, R1, R1sq + R1, 1, R1sq + 1, R1 + 1, R1sq + R1 + 1};
  int totalvb = nuvb + nvb + ntb;

  for (int bid = blockIdx.x; bid < totalvb; bid += gridDim.x) {
    if (bid < nuvb) {
      // ---- uv writer: one aligned float4 per thread (32-bit index math) ----
      u32 chunk = (u32)bid * 256 + tid;
      int e0 = (int)(4u * chunk) - (int)sh;
      if (e0 < (int)totalf) {
        float vals[4];
        bool ok[4];
        bool all4 = true;
#pragma unroll
        for (int j = 0; j < 4; j++) {
          int e = e0 + j;
          bool valid = (e >= 0) && (e < (int)totalf);
          ok[j] = valid;
          all4 &= valid;
          float val = 0.0f;
          if (valid) {
            u32 cell = (u32)e >> 3;
            int comp = e & 7;
            u32 row = cell / NU, col = cell - row * NU;
            float b = (comp & 1) ? (float)((double)row * inv) : (float)((double)col * inv);
            bool addp = (comp == 2) | (comp == 4) | (comp == 5) | (comp == 7);
            val = addp ? b + padf : b;
          }
          vals[j] = val;
        }
        size_t basef = A4 + 4 * (size_t)chunk;
        if (all4) {
          *(float4*)(out + basef) = make_float4(vals[0], vals[1], vals[2], vals[3]);
        } else {
#pragma unroll
          for (int j = 0; j < 4; j++)
            if (ok[j]) out[basef + j] = vals[j];
        }
      }
    } else if (bid < nuvb + nvb) {
      // ---- vertex writer: 1 vertex/thread, rank from lpack ----
      int vb = bid - nuvb;
      int v = vb * 256 + tid;
      if (v < NV) {
        u32 pv = lpack[v];
        u32 m = pv & 0x7fu;
        if (m) {
          u32 r = boffV[vb] + (pv >> 7);
          float sa = sdf[v];
          float pa0 = verts[3 * v + 0] + sdefs * tanhf(deform[3 * v + 0]);
          float pa1 = verts[3 * v + 1] + sdefs * tanhf(deform[3 * v + 1]);
          float pa2 = verts[3 * v + 2] + sdefs * tanhf(deform[3 * v + 2]);
#pragma unroll
          for (int k = 0; k < 7; k++) {
            if ((m >> k) & 1) {
              int b = v + deltas[k];
              float sb = sdf[b];
              float den = sa - sb;  // opposite signs -> no cancellation
              float w0 = -sb / den, w1 = sa / den;
              float pb0 = verts[3 * b + 0] + sdefs * tanhf(deform[3 * b + 0]);
              float pb1 = verts[3 * b + 1] + sdefs * tanhf(deform[3 * b + 1]);
              float pb2 = verts[3 * b + 2] + sdefs * tanhf(deform[3 * b + 2]);
              out[3 * r + 0] = pa0 * w0 + pb0 * w1;
              out[3 * r + 1] = pa1 * w0 + pb1 * w1;
              out[3 * r + 2] = pa2 * w0 + pb2 * w1;
              r++;
            }
          }
        }
      }
    } else {
      // ---- face + uv_idx writer: 1 tet/thread (scan executed uniformly per virtual block) ----
      int tb = bid - nuvb - nvb;
      int t = tb * 256 + tid;
      int code = (t < T) ? (int)tcode[t] : 0;
      int n = c_ntri[code];
      u32 packed = (n == 1 ? 1u : 0u) | (n == 2 ? (1u << 16) : 0u);
      u32 ex = block_exscan_u32(packed, ws, nullptr);
      if (t < T && n > 0) {
        u64 bo = boffT[tb];
        u32 s1 = (u32)bo + (ex & 0xffffu);
        u32 s2 = (u32)(bo >> 32) + (ex >> 16);
        int c = t / 6, k = t - 6 * c;
        int z = c % R, tq = c / R, y = tq % R, x = tq / R;
        int v000 = (x * R1 + y) * R1 + z;
        int g4 = 4 * t;
        for (int tri = 0; tri < n; tri++) {
          u32 row = (n == 1) ? s1 : (F1 + 2u * s2 + (u32)tri);
#pragma unroll
          for (int j = 0; j < 3; j++) {
            int slot = c_tt[code][3 * tri + j];
            int ci = c_kuhn[k][c_e0[slot]], cj = c_kuhn[k][c_e1[slot]];
            int oa = coff[ci], ob = coff[cj];
            int lo = oa < ob ? oa : ob;
            int d = oa < ob ? ob - oa : oa - ob;
            int va = v000 + lo;
            int dx = d >= R1sq ? 1 : 0; d -= dx * R1sq;
            int dy = d >= R1 ? 1 : 0;   d -= dy * R1;     // d now dz in {0,1}
            int kb = (dx << 2) + (dy << 1) + d - 1;       // slot in sorted-Delta order
            u32 pv = lpack[va];
            u32 fidx = boffV[va >> 8] + (pv >> 7) + __popc(pv & 0x7fu & ((1u << kb) - 1u));
            out[fb + 3 * row + j] = (float)fidx;
          }
          out[ub + 3 * row + 0] = (float)g4;
          out[ub + 3 * row + 1] = (float)(g4 + tri + 1);
          out[ub + 3 * row + 2] = (float)(g4 + tri + 2);
        }
      }
    }
  }
}

extern "C" void kernel_launch(void* const* d_in, const int* in_sizes, int n_in,
                              void* d_out, int out_size, void* d_ws, size_t ws_size,
                              hipStream_t stream) {
  const float* verts = (const float*)d_in[0];
  const float* sdf = (const float*)d_in[1];
  const float* deform = (const float*)d_in[2];
  int NV = in_sizes[0] / 3;
  int T = in_sizes[3] / 4;
  int R = 1;
  while ((long long)(R + 1) * (R + 1) * (R + 1) < (long long)NV) R++;
  int NU = 1;
  while ((long long)NU * NU < (long long)T) NU++;   // N = ceil(sqrt((2T+1)//2)) = ceil(sqrt(T))
  int nvb = (NV + 255) / 256;                       // vertex blocks
  int ntb = (T + 255) / 256;                        // tet blocks
  long long nchunks = (8LL * NU * NU) / 4 + 2;      // float4 chunks incl. alignment slop
  int nuvb = (int)((nchunks + 255) / 256);          // uv blocks
  int totalvb = nuvb + nvb + ntb;
  int gD = totalvb < 2048 ? totalvb : 2048;         // persistent: 8 blocks/CU x 256 CUs

  // workspace carve (u64 first for alignment); ~2.8 MB total
  char* w = (char*)d_ws;
  u64* boffT = (u64*)w; w += (size_t)ntb * 8;
  u32* bsumV = (u32*)w; w += (size_t)nvb * 4;
  u32* boffV = (u32*)w; w += (size_t)nvb * 4;
  u32* bsumT = (u32*)w; w += (size_t)ntb * 4;
  u32* lpack = (u32*)w; w += (size_t)nvb * 256 * 4;
  u32* hdr = (u32*)w;   w += 64;
  u8* tcode = (u8*)w;   w += (size_t)T;

  float sdefs = 2.0f / (float)(R * 2);  // 1/64 exact
  double inv = 1.0 / (double)NU;
  float* outf = (float*)d_out;

  if (R == 64 && NU == 1255) {
    kA<64><<<dim3(nvb + ntb), dim3(256), 0, stream>>>(sdf, lpack, tcode, bsumV, bsumT, NV, T, nvb, R);
    kC<<<dim3(2), dim3(1024), 0, stream>>>(bsumV, boffV, nvb, bsumT, boffT, ntb, hdr);
    kD<64, 1255><<<dim3(gD), dim3(256), 0, stream>>>(
        verts, sdf, deform, lpack, boffV, tcode, boffT, hdr, outf,
        NV, T, nvb, nuvb, ntb, R, NU, sdefs, inv);
  } else {
    kA<0><<<dim3(nvb + ntb), dim3(256), 0, stream>>>(sdf, lpack, tcode, bsumV, bsumT, NV, T, nvb, R);
    kC<<<dim3(2), dim3(1024), 0, stream>>>(bsumV, boffV, nvb, bsumT, boffT, ntb, hdr);
    kD<0, 0><<<dim3(gD), dim3(256), 0, stream>>>(
        verts, sdf, deform, lpack, boffV, tcode, boffT, hdr, outf,
        NV, T, nvb, nuvb, ntb, R, NU, sdefs, inv);
  }
}

// Round 9
// 136.513 us; speedup vs baseline: 1.1551x; 1.1551x over previous
//
#include <hip/hip_runtime.h>

typedef unsigned int u32;
typedef unsigned long long u64;
typedef unsigned char u8;

// Marching-tets tables (from reference)
__constant__ int c_tt[16][6] = {
  {-1,-1,-1,-1,-1,-1},{1,0,2,-1,-1,-1},{4,0,3,-1,-1,-1},{1,4,2,1,3,4},
  {3,1,5,-1,-1,-1},{2,3,0,2,5,3},{1,4,0,1,5,4},{4,2,5,-1,-1,-1},
  {4,5,2,-1,-1,-1},{4,1,0,4,5,1},{3,2,0,3,5,2},{1,3,5,-1,-1,-1},
  {4,1,2,4,3,1},{3,0,4,-1,-1,-1},{2,0,1,-1,-1,-1},{-1,-1,-1,-1,-1,-1}};
__constant__ int c_ntri[16] = {0,1,1,2,1,2,2,1,1,2,2,1,2,1,1,0};
__constant__ int c_kuhn[6][4] = {{0,1,3,7},{0,2,3,7},{0,1,5,7},{0,2,6,7},{0,4,5,7},{0,4,6,7}};
__constant__ int c_e0[6] = {0,0,0,1,1,2};
__constant__ int c_e1[6] = {1,2,3,2,3,3};

// ---------------- scan helpers (wave64) ----------------
__device__ __forceinline__ u32 wave_incscan_u32(u32 v) {
  int lane = threadIdx.x & 63;
#pragma unroll
  for (int d = 1; d < 64; d <<= 1) {
    u32 n = __shfl_up(v, (unsigned)d, 64);
    if (lane >= d) v += n;
  }
  return v;
}
__device__ __forceinline__ u64 wave_incscan_u64(u64 v) {
  int lane = threadIdx.x & 63;
#pragma unroll
  for (int d = 1; d < 64; d <<= 1) {
    u32 lo = __shfl_up((u32)v, (unsigned)d, 64);
    u32 hi = __shfl_up((u32)(v >> 32), (unsigned)d, 64);
    u64 n = ((u64)hi << 32) | (u64)lo;
    if (lane >= d) v += n;
  }
  return v;
}
__device__ __forceinline__ u32 block_exscan_u32(u32 v, u32* wsums, u32* total) {
  int tid = threadIdx.x, lane = tid & 63, w = tid >> 6, nw = blockDim.x >> 6;
  u32 inc = wave_incscan_u32(v);
  if (lane == 63) wsums[w] = inc;
  __syncthreads();
  u32 woff = 0, tot = 0;
  for (int i = 0; i < nw; i++) { u32 s = wsums[i]; tot += s; if (i < w) woff += s; }
  __syncthreads();
  if (total) *total = tot;
  return woff + inc - v;
}
__device__ __forceinline__ u64 block_exscan_u64(u64 v, u64* wsums, u64* total) {
  int tid = threadIdx.x, lane = tid & 63, w = tid >> 6, nw = blockDim.x >> 6;
  u64 inc = wave_incscan_u64(v);
  if (lane == 63) wsums[w] = inc;
  __syncthreads();
  u64 woff = 0, tot = 0;
  for (int i = 0; i < nw; i++) { u64 s = wsums[i]; tot += s; if (i < w) woff += s; }
  __syncthreads();
  if (total) *total = tot;
  return woff + inc - v;
}

// ---------------- Kernel A: vertex blocks (lpack + pos4) | cube blocks (tpack + sums) ----------------
// NOTE (R6 lesson): no device fences / same-address tickets — per-XCD L2s are non-coherent; a
// per-block __threadfence()+atomic ticket cost ~470 µs. Separate 2-block kC is ~4 µs.
template <int CR>
__global__ __launch_bounds__(256) void kA(const float* __restrict__ sdf, const float* __restrict__ verts,
                                          const float* __restrict__ deform, float4* __restrict__ pos4,
                                          u32* __restrict__ lpack, u32* __restrict__ tpack,
                                          u32* __restrict__ bsumV, u32* __restrict__ bsumT,
                                          int NV, int Tc, int nvb, int rr, float sdefs) {
  const int R = CR ? CR : rr;
  const int R1 = R + 1, R1sq = R1 * R1;
  __shared__ u32 ws[4];
  int tid = threadIdx.x, bid = blockIdx.x;
  if (bid < nvb) {
    // ---- vertex part: crossing mask + block-local edge rank + deformed position (+sdf) ----
    int v = bid * 256 + tid;
    u32 m = 0;
    float s = 0.0f;
    if (v < NV) {
      int z = v % R1, tq = v / R1, y = tq % R1, x = tq / R1;
      s = sdf[v];
      bool o = s > 0.0f;
      bool bx = x < R, by = y < R, bz = z < R;
      if (bz && (sdf[v + 1] > 0.0f) != o) m |= 1;
      if (by && (sdf[v + R1] > 0.0f) != o) m |= 2;
      if (by && bz && (sdf[v + R1 + 1] > 0.0f) != o) m |= 4;
      if (bx && (sdf[v + R1sq] > 0.0f) != o) m |= 8;
      if (bx && bz && (sdf[v + R1sq + 1] > 0.0f) != o) m |= 16;
      if (bx && by && (sdf[v + R1sq + R1] > 0.0f) != o) m |= 32;
      if (bx && by && bz && (sdf[v + R1sq + R1 + 1] > 0.0f) != o) m |= 64;
    }
    u32 tot;
    u32 ex = block_exscan_u32(__popc(m), ws, &tot);
    if (v < NV) {
      lpack[v] = (ex << 7) | m;
      float4 p;
      p.x = verts[3 * v + 0] + sdefs * tanhf(deform[3 * v + 0]);
      p.y = verts[3 * v + 1] + sdefs * tanhf(deform[3 * v + 1]);
      p.z = verts[3 * v + 2] + sdefs * tanhf(deform[3 * v + 2]);
      p.w = s;
      pos4[v] = p;
    }
    if (tid == 0) bsumV[bid] = tot;
  } else {
    // ---- cube part: 1 thread/cube; 8 z-coalesced sdf loads -> 6 tet codes + local ranks ----
    int bid2 = bid - nvb;
    int c = bid2 * 256 + tid;
    u32 pk = 0;
    u32 b = 0;
    int codes[6];
    if (c < Tc) {
      int z = c % R, tq = c / R, y = tq % R, x = tq / R;
      int v000 = (x * R1 + y) * R1 + z;
      int coff[8] = {0, R1sq, R1, R1sq + R1, 1, R1sq + 1, R1 + 1, R1sq + R1 + 1};
#pragma unroll
      for (int j = 0; j < 8; j++) b |= (sdf[v000 + coff[j]] > 0.0f ? 1u : 0u) << j;
#pragma unroll
      for (int k = 0; k < 6; k++) {
        int code = ((b >> c_kuhn[k][0]) & 1) | (((b >> c_kuhn[k][1]) & 1) << 1) |
                   (((b >> c_kuhn[k][2]) & 1) << 2) | (((b >> c_kuhn[k][3]) & 1) << 3);
        codes[k] = code;
        int n = c_ntri[code];
        pk += (n == 1 ? 1u : 0u) + (n == 2 ? (1u << 16) : 0u);
      }
    }
    u32 tot;
    u32 ex = block_exscan_u32(pk, ws, &tot);
    if (c < Tc) {
      u32 r1 = ex & 0xffffu, r2 = ex >> 16;
      u32 tp[6];
#pragma unroll
      for (int k = 0; k < 6; k++) {
        int code = codes[k];
        tp[k] = (u32)code | (r1 << 4) | (r2 << 15);   // 4 + 11 + 11 bits (ranks < 1536)
        int n = c_ntri[code];
        r1 += (n == 1);
        r2 += (n == 2);
      }
      u32* dst = tpack + 6 * c;                        // 8B-aligned (24c bytes)
      *(uint2*)(dst + 0) = make_uint2(tp[0], tp[1]);
      *(uint2*)(dst + 2) = make_uint2(tp[2], tp[3]);
      *(uint2*)(dst + 4) = make_uint2(tp[4], tp[5]);
    }
    if (tid == 0) bsumT[bid2] = tot;                   // m1 | m2<<16 per cube-block
  }
}

// ---------------- Kernel C: two independent aux scans ----------------
__global__ __launch_bounds__(1024) void kC(const u32* __restrict__ bsumV, u32* __restrict__ boffV,
                                           int nvb, const u32* __restrict__ bsumT,
                                           u64* __restrict__ boffT, int ncb, u32* __restrict__ hdr) {
  if (blockIdx.x == 0) {
    __shared__ u32 ws32[16];
    u32 carry = 0;
    for (int base = 0; base < nvb; base += 1024) {
      int i = base + threadIdx.x;
      u32 v = (i < nvb) ? bsumV[i] : 0;
      u32 tot;
      u32 ex = block_exscan_u32(v, ws32, &tot);
      if (i < nvb) boffV[i] = carry + ex;
      carry += tot;
    }
    if (threadIdx.x == 0) hdr[0] = carry;               // E
  } else {
    __shared__ u64 ws64[16];
    u64 carry = 0;
    for (int base = 0; base < ncb; base += 1024) {
      int i = base + threadIdx.x;
      u32 p = (i < ncb) ? bsumT[i] : 0;
      u64 v = (u64)(p & 0xffffu) | ((u64)(p >> 16) << 32);
      u64 tot;
      u64 ex = block_exscan_u64(v, ws64, &tot);
      if (i < ncb) boffT[i] = carry + ex;
      carry += tot;
    }
    if (threadIdx.x == 0) { hdr[1] = (u32)carry; hdr[2] = (u32)(carry >> 32); } // F1, F2
  }
}

// ---------------- Kernel D: uv | verts | faces — scan-free, barrier-free, one concurrent grid ------
template <int CR, int CNU>
__global__ __launch_bounds__(256) void kD(const float4* __restrict__ pos4, const u32* __restrict__ lpack,
                                          const u32* __restrict__ boffV, const u32* __restrict__ tpack,
                                          const u64* __restrict__ boffT, const u32* __restrict__ hdr,
                                          float* __restrict__ out, int NV, int T, int nvb, int nuvb,
                                          int rr, int nuu, double inv) {
  const int R = CR ? CR : rr;
  const int R1 = R + 1, R1sq = R1 * R1;
  const u32 NU = CNU ? CNU : (u32)nuu;
  int tid = threadIdx.x, bid = blockIdx.x;
  u32 E = hdr[0], F1 = hdr[1], F2 = hdr[2];
  u32 F = F1 + 2u * F2;
  size_t fb = (size_t)3 * E;                     // faces section start (float index)
  size_t A = fb + (size_t)3 * F;                 // uvs section start
  size_t ub = A + (size_t)8 * NU * NU;           // uv_idx section start
  if (bid < nuvb) {
    // ---- uv writer: 8 floats/thread, ONE div, wave-uniform phase switch, two float4 stores ----
    u32 chunk = (u32)bid * 256 + tid;
    u32 sh = (u32)(A & 3);
    int totalf = (int)(8u * NU * NU);            // < 2^31
    int e0 = (int)(8u * chunk) - (int)sh;
    if (e0 >= totalf) return;
    float padf = (float)(0.9 * inv);
    // cell1 = chunk; cell0 = chunk-1 (only used when sh>0)
    u32 row1 = chunk / NU, col1 = chunk - row1 * NU;
    u32 col0 = (col1 == 0) ? (NU - 1) : (col1 - 1);
    u32 row0 = (col1 == 0) ? (row1 - 1) : row1;
    float x1 = (float)((double)col1 * inv), y1 = (float)((double)row1 * inv);
    float xp1 = x1 + padf, yp1 = y1 + padf;
    float x0 = (float)((double)col0 * inv), y0 = (float)((double)row0 * inv);
    float xp0 = x0 + padf, yp0 = y0 + padf;
    (void)xp0;
    // per-cell comp order: {x, y, xp, y, xp, yp, x, yp}
    float vals[8];
    switch (sh) {
      case 0: vals[0]=x1; vals[1]=y1; vals[2]=xp1; vals[3]=y1; vals[4]=xp1; vals[5]=yp1; vals[6]=x1; vals[7]=yp1; break;
      case 1: vals[0]=yp0; vals[1]=x1; vals[2]=y1; vals[3]=xp1; vals[4]=y1; vals[5]=xp1; vals[6]=yp1; vals[7]=x1; break;
      case 2: vals[0]=x0; vals[1]=yp0; vals[2]=x1; vals[3]=y1; vals[4]=xp1; vals[5]=y1; vals[6]=xp1; vals[7]=yp1; break;
      default: vals[0]=yp0; vals[1]=x0; vals[2]=yp0; vals[3]=x1; vals[4]=y1; vals[5]=xp1; vals[6]=y1; vals[7]=xp1; break;
    }
    size_t basef = (A - sh) + 8 * (size_t)chunk;
    if (e0 >= 0 && e0 + 7 < totalf) {
      *(float4*)(out + basef)     = make_float4(vals[0], vals[1], vals[2], vals[3]);
      *(float4*)(out + basef + 4) = make_float4(vals[4], vals[5], vals[6], vals[7]);
    } else {
#pragma unroll
      for (int j = 0; j < 8; j++) {
        int e = e0 + j;
        if (e >= 0 && e < totalf) out[basef + j] = vals[j];
      }
    }
  } else if (bid < nuvb + nvb) {
    // ---- vertex writer: 1 vertex/thread; pos4 carries deformed xyz + sdf ----
    int vb = bid - nuvb;
    int v = vb * 256 + tid;
    if (v >= NV) return;
    u32 pv = lpack[v];
    u32 m = pv & 0x7fu;
    if (!m) return;
    u32 r = boffV[vb] + (pv >> 7);
    int deltas[7] = {1, R1, R1 + 1, R1sq, R1sq + 1, R1sq + R1, R1sq + R1 + 1};
    float4 a4 = pos4[v];
#pragma unroll
    for (int k = 0; k < 7; k++) {
      if ((m >> k) & 1) {
        float4 b4 = pos4[v + deltas[k]];
        float den = a4.w - b4.w;        // opposite signs -> no cancellation
        float w0 = -b4.w / den, w1 = a4.w / den;
        out[3 * r + 0] = a4.x * w0 + b4.x * w1;
        out[3 * r + 1] = a4.y * w0 + b4.y * w1;
        out[3 * r + 2] = a4.z * w0 + b4.z * w1;
        r++;
      }
    }
  } else {
    // ---- face + uv_idx writer: 1 tet/thread, scan-free via tpack local ranks ----
    int tb = bid - nuvb - nvb;
    int t = tb * 256 + tid;
    if (t >= T) return;
    u32 tp = tpack[t];
    int code = (int)(tp & 0xfu);
    int n = c_ntri[code];
    if (n == 0) return;
    u64 bo = boffT[tb / 6];                        // cube-block id (1536 tets = 6 face blocks)
    u32 s1 = (u32)bo + ((tp >> 4) & 0x7ffu);
    u32 s2 = (u32)(bo >> 32) + ((tp >> 15) & 0x7ffu);
    int c = t / 6, k = t - 6 * c;
    int z = c % R, tq = c / R, y = tq % R, x = tq / R;
    int v000 = (x * R1 + y) * R1 + z;
    int coff[8] = {0, R1sq, R1, R1sq + R1, 1, R1sq + 1, R1 + 1, R1sq + R1 + 1};
    int g4 = 4 * t;
    for (int tri = 0; tri < n; tri++) {
      u32 row = (n == 1) ? s1 : (F1 + 2u * s2 + (u32)tri);
#pragma unroll
      for (int j = 0; j < 3; j++) {
        int slot = c_tt[code][3 * tri + j];
        int ci = c_kuhn[k][c_e0[slot]], cj = c_kuhn[k][c_e1[slot]];
        int oa = coff[ci], ob = coff[cj];
        int lo = oa < ob ? oa : ob;
        int d = oa < ob ? ob - oa : oa - ob;
        int va = v000 + lo;
        int dx = d >= R1sq ? 1 : 0; d -= dx * R1sq;
        int dy = d >= R1 ? 1 : 0;   d -= dy * R1;     // d now dz in {0,1}
        int kb = (dx << 2) + (dy << 1) + d - 1;       // slot in sorted-Delta order
        u32 pv = lpack[va];
        u32 fidx = boffV[va >> 8] + (pv >> 7) + __popc(pv & 0x7fu & ((1u << kb) - 1u));
        out[fb + 3 * row + j] = (float)fidx;
      }
      out[ub + 3 * row + 0] = (float)g4;
      out[ub + 3 * row + 1] = (float)(g4 + tri + 1);
      out[ub + 3 * row + 2] = (float)(g4 + tri + 2);
    }
  }
}

extern "C" void kernel_launch(void* const* d_in, const int* in_sizes, int n_in,
                              void* d_out, int out_size, void* d_ws, size_t ws_size,
                              hipStream_t stream) {
  const float* verts = (const float*)d_in[0];
  const float* sdf = (const float*)d_in[1];
  const float* deform = (const float*)d_in[2];
  int NV = in_sizes[0] / 3;
  int T = in_sizes[3] / 4;
  int R = 1;
  while ((long long)(R + 1) * (R + 1) * (R + 1) < (long long)NV) R++;
  int NU = 1;
  while ((long long)NU * NU < (long long)T) NU++;   // N = ceil(sqrt((2T+1)//2)) = ceil(sqrt(T))
  int Tc = T / 6;                                   // cubes
  int nvb = (NV + 255) / 256;                       // vertex blocks
  int ncb = (Tc + 255) / 256;                       // cube blocks (kA) / cube-block scan entries
  int ntb = (T + 255) / 256;                        // tet (face) blocks in kD
  long long nchunks = (long long)NU * NU + 1;       // 8-float chunks incl. alignment slop
  int nuvb = (int)((nchunks + 255) / 256);          // uv blocks

  // workspace carve (16B-aligned first); ~12 MB total
  char* w = (char*)d_ws;
  float4* pos4 = (float4*)w; w += (size_t)nvb * 256 * 16;
  u64* boffT = (u64*)w; w += (size_t)ncb * 8;
  u32* tpack = (u32*)w; w += (size_t)T * 4;
  u32* bsumV = (u32*)w; w += (size_t)nvb * 4;
  u32* boffV = (u32*)w; w += (size_t)nvb * 4;
  u32* bsumT = (u32*)w; w += (size_t)ncb * 4;
  u32* lpack = (u32*)w; w += (size_t)nvb * 256 * 4;
  u32* hdr = (u32*)w;   w += 64;

  float sdefs = 2.0f / (float)(R * 2);  // 1/64 exact
  double inv = 1.0 / (double)NU;
  float* outf = (float*)d_out;

  if (R == 64 && NU == 1255) {
    kA<64><<<dim3(nvb + ncb), dim3(256), 0, stream>>>(sdf, verts, deform, pos4, lpack, tpack,
                                                      bsumV, bsumT, NV, Tc, nvb, R, sdefs);
    kC<<<dim3(2), dim3(1024), 0, stream>>>(bsumV, boffV, nvb, bsumT, boffT, ncb, hdr);
    kD<64, 1255><<<dim3(nuvb + nvb + ntb), dim3(256), 0, stream>>>(
        pos4, lpack, boffV, tpack, boffT, hdr, outf, NV, T, nvb, nuvb, R, NU, inv);
  } else {
    kA<0><<<dim3(nvb + ncb), dim3(256), 0, stream>>>(sdf, verts, deform, pos4, lpack, tpack,
                                                     bsumV, bsumT, NV, Tc, nvb, R, sdefs);
    kC<<<dim3(2), dim3(1024), 0, stream>>>(bsumV, boffV, nvb, bsumT, boffT, ncb, hdr);
    kD<0, 0><<<dim3(nuvb + nvb + ntb), dim3(256), 0, stream>>>(
        pos4, lpack, boffV, tpack, boffT, hdr, outf, NV, T, nvb, nuvb, R, NU, inv);
  }
}

// Round 10
// 136.336 us; speedup vs baseline: 1.1566x; 1.0013x over previous
//
#include <hip/hip_runtime.h>

typedef unsigned int u32;
typedef unsigned long long u64;
typedef unsigned char u8;

// Marching-tets tables (from reference)
__constant__ int c_tt[16][6] = {
  {-1,-1,-1,-1,-1,-1},{1,0,2,-1,-1,-1},{4,0,3,-1,-1,-1},{1,4,2,1,3,4},
  {3,1,5,-1,-1,-1},{2,3,0,2,5,3},{1,4,0,1,5,4},{4,2,5,-1,-1,-1},
  {4,5,2,-1,-1,-1},{4,1,0,4,5,1},{3,2,0,3,5,2},{1,3,5,-1,-1,-1},
  {4,1,2,4,3,1},{3,0,4,-1,-1,-1},{2,0,1,-1,-1,-1},{-1,-1,-1,-1,-1,-1}};
__constant__ int c_kuhn[6][4] = {{0,1,3,7},{0,2,3,7},{0,1,5,7},{0,2,6,7},{0,4,5,7},{0,4,6,7}};
__constant__ int c_e0[6] = {0,0,0,1,1,2};
__constant__ int c_e1[6] = {1,2,3,2,3,3};

// ntri via bitmask (verified vs NUM_TRIANGLES_TABLE for all 16 codes):
// n==1 codes {1,2,4,7,8,11,13,14} -> 0x6996 ; n==2 codes {3,5,6,9,10,12} -> 0x1668
#define N1BIT(code) ((0x6996u >> (code)) & 1u)
#define N2BIT(code) ((0x1668u >> (code)) & 1u)

// ---------------- scan helpers (wave64) ----------------
__device__ __forceinline__ u32 wave_incscan_u32(u32 v) {
  int lane = threadIdx.x & 63;
#pragma unroll
  for (int d = 1; d < 64; d <<= 1) {
    u32 n = __shfl_up(v, (unsigned)d, 64);
    if (lane >= d) v += n;
  }
  return v;
}
__device__ __forceinline__ u64 wave_incscan_u64(u64 v) {
  int lane = threadIdx.x & 63;
#pragma unroll
  for (int d = 1; d < 64; d <<= 1) {
    u32 lo = __shfl_up((u32)v, (unsigned)d, 64);
    u32 hi = __shfl_up((u32)(v >> 32), (unsigned)d, 64);
    u64 n = ((u64)hi << 32) | (u64)lo;
    if (lane >= d) v += n;
  }
  return v;
}
__device__ __forceinline__ u32 block_exscan_u32(u32 v, u32* wsums, u32* total) {
  int tid = threadIdx.x, lane = tid & 63, w = tid >> 6, nw = blockDim.x >> 6;
  u32 inc = wave_incscan_u32(v);
  if (lane == 63) wsums[w] = inc;
  __syncthreads();
  u32 woff = 0, tot = 0;
  for (int i = 0; i < nw; i++) { u32 s = wsums[i]; tot += s; if (i < w) woff += s; }
  __syncthreads();
  if (total) *total = tot;
  return woff + inc - v;
}
__device__ __forceinline__ u64 block_exscan_u64(u64 v, u64* wsums, u64* total) {
  int tid = threadIdx.x, lane = tid & 63, w = tid >> 6, nw = blockDim.x >> 6;
  u64 inc = wave_incscan_u64(v);
  if (lane == 63) wsums[w] = inc;
  __syncthreads();
  u64 woff = 0, tot = 0;
  for (int i = 0; i < nw; i++) { u64 s = wsums[i]; tot += s; if (i < w) woff += s; }
  __syncthreads();
  if (total) *total = tot;
  return woff + inc - v;
}

// ---------------- Kernel A: vertex blocks (lpack + pos4) | cube blocks (cpack + sums) ----------------
// NOTE (R6 lesson): no device fences / same-address tickets — per-XCD L2s are non-coherent; a
// per-block __threadfence()+atomic ticket cost ~470 µs. Separate 2-block kC is ~4 µs.
template <int CR>
__global__ __launch_bounds__(256) void kA(const float* __restrict__ sdf, const float* __restrict__ verts,
                                          const float* __restrict__ deform, float4* __restrict__ pos4,
                                          u32* __restrict__ lpack, u32* __restrict__ cpack,
                                          u32* __restrict__ bsumV, u32* __restrict__ bsumT,
                                          int NV, int Tc, int nvb, int rr, float sdefs) {
  const int R = CR ? CR : rr;
  const int R1 = R + 1, R1sq = R1 * R1;
  __shared__ u32 ws[4];
  int tid = threadIdx.x, bid = blockIdx.x;
  if (bid < nvb) {
    // ---- vertex part: crossing mask + block-local edge rank + deformed position (+sdf) ----
    int v = bid * 256 + tid;
    u32 m = 0;
    float s = 0.0f;
    if (v < NV) {
      int z = v % R1, tq = v / R1, y = tq % R1, x = tq / R1;
      s = sdf[v];
      bool o = s > 0.0f;
      bool bx = x < R, by = y < R, bz = z < R;
      if (bz && (sdf[v + 1] > 0.0f) != o) m |= 1;
      if (by && (sdf[v + R1] > 0.0f) != o) m |= 2;
      if (by && bz && (sdf[v + R1 + 1] > 0.0f) != o) m |= 4;
      if (bx && (sdf[v + R1sq] > 0.0f) != o) m |= 8;
      if (bx && bz && (sdf[v + R1sq + 1] > 0.0f) != o) m |= 16;
      if (bx && by && (sdf[v + R1sq + R1] > 0.0f) != o) m |= 32;
      if (bx && by && bz && (sdf[v + R1sq + R1 + 1] > 0.0f) != o) m |= 64;
    }
    u32 tot;
    u32 ex = block_exscan_u32(__popc(m), ws, &tot);
    if (v < NV) {
      lpack[v] = (ex << 7) | m;
      float4 p;
      p.x = verts[3 * v + 0] + sdefs * tanhf(deform[3 * v + 0]);
      p.y = verts[3 * v + 1] + sdefs * tanhf(deform[3 * v + 1]);
      p.z = verts[3 * v + 2] + sdefs * tanhf(deform[3 * v + 2]);
      p.w = s;
      pos4[v] = p;
    }
    if (tid == 0) bsumV[bid] = tot;
  } else {
    // ---- cube part: 1 thread/cube; 8 z-coalesced sdf loads -> corner mask + local ranks ----
    int bid2 = bid - nvb;
    int c = bid2 * 256 + tid;
    u32 pk = 0;
    u32 b = 0;
    if (c < Tc) {
      int z = c % R, tq = c / R, y = tq % R, x = tq / R;
      int v000 = (x * R1 + y) * R1 + z;
      int coff[8] = {0, R1sq, R1, R1sq + R1, 1, R1sq + 1, R1 + 1, R1sq + R1 + 1};
#pragma unroll
      for (int j = 0; j < 8; j++) b |= (sdf[v000 + coff[j]] > 0.0f ? 1u : 0u) << j;
#pragma unroll
      for (int k = 0; k < 6; k++) {
        int code = ((b >> c_kuhn[k][0]) & 1) | (((b >> c_kuhn[k][1]) & 1) << 1) |
                   (((b >> c_kuhn[k][2]) & 1) << 2) | (((b >> c_kuhn[k][3]) & 1) << 3);
        pk += N1BIT(code) + (N2BIT(code) << 16);
      }
    }
    u32 tot;
    u32 ex = block_exscan_u32(pk, ws, &tot);
    if (c < Tc) {
      u32 r1 = ex & 0xffffu, r2 = ex >> 16;        // block-local ranks, < 1536 (11 bits)
      cpack[c] = b | (r1 << 8) | (r2 << 19);       // 8 + 11 + 11 bits
    }
    if (tid == 0) bsumT[bid2] = tot;               // m1 | m2<<16 per cube-block
  }
}

// ---------------- Kernel C: two independent aux scans ----------------
__global__ __launch_bounds__(1024) void kC(const u32* __restrict__ bsumV, u32* __restrict__ boffV,
                                           int nvb, const u32* __restrict__ bsumT,
                                           u64* __restrict__ boffT, int ncb, u32* __restrict__ hdr) {
  if (blockIdx.x == 0) {
    __shared__ u32 ws32[16];
    u32 carry = 0;
    for (int base = 0; base < nvb; base += 1024) {
      int i = base + threadIdx.x;
      u32 v = (i < nvb) ? bsumV[i] : 0;
      u32 tot;
      u32 ex = block_exscan_u32(v, ws32, &tot);
      if (i < nvb) boffV[i] = carry + ex;
      carry += tot;
    }
    if (threadIdx.x == 0) hdr[0] = carry;               // E
  } else {
    __shared__ u64 ws64[16];
    u64 carry = 0;
    for (int base = 0; base < ncb; base += 1024) {
      int i = base + threadIdx.x;
      u32 p = (i < ncb) ? bsumT[i] : 0;
      u64 v = (u64)(p & 0xffffu) | ((u64)(p >> 16) << 32);
      u64 tot;
      u64 ex = block_exscan_u64(v, ws64, &tot);
      if (i < ncb) boffT[i] = carry + ex;
      carry += tot;
    }
    if (threadIdx.x == 0) { hdr[1] = (u32)carry; hdr[2] = (u32)(carry >> 32); } // F1, F2
  }
}

// ---------------- Kernel D: uv | verts | faces — scan-free, barrier-free, one concurrent grid ------
template <int CR, int CNU>
__global__ __launch_bounds__(256) void kD(const float4* __restrict__ pos4, const u32* __restrict__ lpack,
                                          const u32* __restrict__ boffV, const u32* __restrict__ cpack,
                                          const u64* __restrict__ boffT, const u32* __restrict__ hdr,
                                          float* __restrict__ out, int NV, int T, int nvb, int nuvb,
                                          int rr, int nuu, double inv) {
  const int R = CR ? CR : rr;
  const int R1 = R + 1, R1sq = R1 * R1;
  const u32 NU = CNU ? CNU : (u32)nuu;
  int tid = threadIdx.x, bid = blockIdx.x;
  u32 E = hdr[0], F1 = hdr[1], F2 = hdr[2];
  u32 F = F1 + 2u * F2;
  size_t fb = (size_t)3 * E;                     // faces section start (float index)
  size_t A = fb + (size_t)3 * F;                 // uvs section start
  size_t ub = A + (size_t)8 * NU * NU;           // uv_idx section start
  if (bid < nuvb) {
    // ---- uv writer: 8 floats/thread, ONE div, wave-uniform phase switch, two float4 stores ----
    u32 chunk = (u32)bid * 256 + tid;
    u32 sh = (u32)(A & 3);
    int totalf = (int)(8u * NU * NU);            // < 2^31
    int e0 = (int)(8u * chunk) - (int)sh;
    if (e0 >= totalf) return;
    float padf = (float)(0.9 * inv);
    // cell1 = chunk; cell0 = chunk-1 (only used when sh>0)
    u32 row1 = chunk / NU, col1 = chunk - row1 * NU;
    u32 col0 = (col1 == 0) ? (NU - 1) : (col1 - 1);
    u32 row0 = (col1 == 0) ? (row1 - 1) : row1;
    float x1 = (float)((double)col1 * inv), y1 = (float)((double)row1 * inv);
    float xp1 = x1 + padf, yp1 = y1 + padf;
    float x0 = (float)((double)col0 * inv), y0 = (float)((double)row0 * inv);
    float yp0 = y0 + padf;
    // per-cell comp order: {x, y, xp, y, xp, yp, x, yp}
    float vals[8];
    switch (sh) {
      case 0: vals[0]=x1; vals[1]=y1; vals[2]=xp1; vals[3]=y1; vals[4]=xp1; vals[5]=yp1; vals[6]=x1; vals[7]=yp1; break;
      case 1: vals[0]=yp0; vals[1]=x1; vals[2]=y1; vals[3]=xp1; vals[4]=y1; vals[5]=xp1; vals[6]=yp1; vals[7]=x1; break;
      case 2: vals[0]=x0; vals[1]=yp0; vals[2]=x1; vals[3]=y1; vals[4]=xp1; vals[5]=y1; vals[6]=xp1; vals[7]=yp1; break;
      default: vals[0]=yp0; vals[1]=x0; vals[2]=yp0; vals[3]=x1; vals[4]=y1; vals[5]=xp1; vals[6]=y1; vals[7]=xp1; break;
    }
    size_t basef = (A - sh) + 8 * (size_t)chunk;
    if (e0 >= 0 && e0 + 7 < totalf) {
      *(float4*)(out + basef)     = make_float4(vals[0], vals[1], vals[2], vals[3]);
      *(float4*)(out + basef + 4) = make_float4(vals[4], vals[5], vals[6], vals[7]);
    } else {
#pragma unroll
      for (int j = 0; j < 8; j++) {
        int e = e0 + j;
        if (e >= 0 && e < totalf) out[basef + j] = vals[j];
      }
    }
  } else if (bid < nuvb + nvb) {
    // ---- vertex writer: 1 vertex/thread; pos4 carries deformed xyz + sdf ----
    int vb = bid - nuvb;
    int v = vb * 256 + tid;
    if (v >= NV) return;
    u32 pv = lpack[v];
    u32 m = pv & 0x7fu;
    if (!m) return;
    u32 r = boffV[vb] + (pv >> 7);
    int deltas[7] = {1, R1, R1 + 1, R1sq, R1sq + 1, R1sq + R1, R1sq + R1 + 1};
    float4 a4 = pos4[v];
#pragma unroll
    for (int k = 0; k < 7; k++) {
      if ((m >> k) & 1) {
        float4 b4 = pos4[v + deltas[k]];
        float den = a4.w - b4.w;        // opposite signs -> no cancellation
        float w0 = -b4.w / den, w1 = a4.w / den;
        out[3 * r + 0] = a4.x * w0 + b4.x * w1;
        out[3 * r + 1] = a4.y * w0 + b4.y * w1;
        out[3 * r + 2] = a4.z * w0 + b4.z * w1;
        r++;
      }
    }
  } else {
    // ---- face + uv_idx writer: 1 tet/thread; code + intra-cube rank decoded from cpack ----
    int tb = bid - nuvb - nvb;
    int t = tb * 256 + tid;
    if (t >= T) return;
    int c = t / 6, k = t - 6 * c;
    u32 cp = cpack[c];                             // 6 consecutive threads share one word
    u32 b = cp & 0xffu;
    if (b == 0u || b == 0xffu) return;             // whole cube uniform -> all 6 tets empty
    int code = 0;
    u32 a1 = 0, a2 = 0;
#pragma unroll
    for (int j = 0; j < 6; j++) {
      int cj = ((b >> c_kuhn[j][0]) & 1) | (((b >> c_kuhn[j][1]) & 1) << 1) |
               (((b >> c_kuhn[j][2]) & 1) << 2) | (((b >> c_kuhn[j][3]) & 1) << 3);
      if (j < k) { a1 += N1BIT(cj); a2 += N2BIT(cj); }
      if (j == k) code = cj;
    }
    int n = (int)(N1BIT(code) + 2u * N2BIT(code));
    if (n == 0) return;
    u64 bo = boffT[c >> 8];                        // cube-block id
    u32 s1 = (u32)bo + ((cp >> 8) & 0x7ffu) + a1;
    u32 s2 = (u32)(bo >> 32) + (cp >> 19) + a2;
    int z = c % R, tq = c / R, y = tq % R, x = tq / R;
    int v000 = (x * R1 + y) * R1 + z;
    int coff[8] = {0, R1sq, R1, R1sq + R1, 1, R1sq + 1, R1 + 1, R1sq + R1 + 1};
    int g4 = 4 * t;
    for (int tri = 0; tri < n; tri++) {
      u32 row = (n == 1) ? s1 : (F1 + 2u * s2 + (u32)tri);
#pragma unroll
      for (int j = 0; j < 3; j++) {
        int slot = c_tt[code][3 * tri + j];
        int ci = c_kuhn[k][c_e0[slot]], cj = c_kuhn[k][c_e1[slot]];
        int oa = coff[ci], ob = coff[cj];
        int lo = oa < ob ? oa : ob;
        int d = oa < ob ? ob - oa : oa - ob;
        int va = v000 + lo;
        int dx = d >= R1sq ? 1 : 0; d -= dx * R1sq;
        int dy = d >= R1 ? 1 : 0;   d -= dy * R1;     // d now dz in {0,1}
        int kb = (dx << 2) + (dy << 1) + d - 1;       // slot in sorted-Delta order
        u32 pv = lpack[va];
        u32 fidx = boffV[va >> 8] + (pv >> 7) + __popc(pv & 0x7fu & ((1u << kb) - 1u));
        out[fb + 3 * row + j] = (float)fidx;
      }
      out[ub + 3 * row + 0] = (float)g4;
      out[ub + 3 * row + 1] = (float)(g4 + tri + 1);
      out[ub + 3 * row + 2] = (float)(g4 + tri + 2);
    }
  }
}

extern "C" void kernel_launch(void* const* d_in, const int* in_sizes, int n_in,
                              void* d_out, int out_size, void* d_ws, size_t ws_size,
                              hipStream_t stream) {
  const float* verts = (const float*)d_in[0];
  const float* sdf = (const float*)d_in[1];
  const float* deform = (const float*)d_in[2];
  int NV = in_sizes[0] / 3;
  int T = in_sizes[3] / 4;
  int R = 1;
  while ((long long)(R + 1) * (R + 1) * (R + 1) < (long long)NV) R++;
  int NU = 1;
  while ((long long)NU * NU < (long long)T) NU++;   // N = ceil(sqrt((2T+1)//2)) = ceil(sqrt(T))
  int Tc = T / 6;                                   // cubes
  int nvb = (NV + 255) / 256;                       // vertex blocks
  int ncb = (Tc + 255) / 256;                       // cube blocks (kA) / scan entries
  int ntb = (T + 255) / 256;                        // tet (face) blocks in kD
  long long nchunks = (long long)NU * NU + 1;       // 8-float chunks incl. alignment slop
  int nuvb = (int)((nchunks + 255) / 256);          // uv blocks

  // workspace carve (16B-aligned first); ~7 MB total
  char* w = (char*)d_ws;
  float4* pos4 = (float4*)w; w += (size_t)nvb * 256 * 16;
  u64* boffT = (u64*)w; w += (size_t)ncb * 8;
  u32* cpack = (u32*)w; w += (size_t)Tc * 4;
  u32* bsumV = (u32*)w; w += (size_t)nvb * 4;
  u32* boffV = (u32*)w; w += (size_t)nvb * 4;
  u32* bsumT = (u32*)w; w += (size_t)ncb * 4;
  u32* lpack = (u32*)w; w += (size_t)nvb * 256 * 4;
  u32* hdr = (u32*)w;   w += 64;

  float sdefs = 2.0f / (float)(R * 2);  // 1/64 exact
  double inv = 1.0 / (double)NU;
  float* outf = (float*)d_out;

  if (R == 64 && NU == 1255) {
    kA<64><<<dim3(nvb + ncb), dim3(256), 0, stream>>>(sdf, verts, deform, pos4, lpack, cpack,
                                                      bsumV, bsumT, NV, Tc, nvb, R, sdefs);
    kC<<<dim3(2), dim3(1024), 0, stream>>>(bsumV, boffV, nvb, bsumT, boffT, ncb, hdr);
    kD<64, 1255><<<dim3(nuvb + nvb + ntb), dim3(256), 0, stream>>>(
        pos4, lpack, boffV, cpack, boffT, hdr, outf, NV, T, nvb, nuvb, R, NU, inv);
  } else {
    kA<0><<<dim3(nvb + ncb), dim3(256), 0, stream>>>(sdf, verts, deform, pos4, lpack, cpack,
                                                     bsumV, bsumT, NV, Tc, nvb, R, sdefs);
    kC<<<dim3(2), dim3(1024), 0, stream>>>(bsumV, boffV, nvb, bsumT, boffT, ncb, hdr);
    kD<0, 0><<<dim3(nuvb + nvb + ntb), dim3(256), 0, stream>>>(
        pos4, lpack, boffV, cpack, boffT, hdr, outf, NV, T, nvb, nuvb, R, NU, inv);
  }
}